// Round 5
// baseline (796.009 us; speedup 1.0000x reference)
//
#include <hip/hip_runtime.h>
#include <math.h>

#define UNITS 1024
#define EMBD  256
#define BATCH 64
#define TLEN  128
#define VOCAB 32000
#define GIN_D (UNITS + EMBD)   // 1280

typedef short short8 __attribute__((ext_vector_type(8)));
typedef float f32x4  __attribute__((ext_vector_type(4)));

__device__ __forceinline__ unsigned short f2bf(float f) {
    unsigned int u = __float_as_uint(f);
    u += 0x7fffu + ((u >> 16) & 1u);   // RNE
    return (unsigned short)(u >> 16);
}
__device__ __forceinline__ unsigned int packbf(float lo, float hi) {
    return (unsigned int)f2bf(lo) | ((unsigned int)f2bf(hi) << 16);
}

// ---------------- K1: c[b,j] = hidden[b,:]@W2[:,j] + b1[j] + b2[j] ------------------
// block = 64 j-cols x 16 batches (4/thread), full K. hidden chunk in LDS.
__global__ __launch_bounds__(256) void k_c(const float* __restrict__ hidden,
                                           const float* __restrict__ W2,
                                           const float* __restrict__ b1,
                                           const float* __restrict__ b2,
                                           float* __restrict__ c) {
    __shared__ float hT[16 * 68];      // [b][k] chunk, 64 k, pad 68
    const int t    = threadIdx.x;
    const int lane = t & 63;
    const int wid  = t >> 6;
    const int j    = blockIdx.x * 64 + lane;
    const int bb   = blockIdx.y * 16;  // batch group base
    const int b0   = wid * 4;          // this wave's 4 batches (within group)

    float acc[4] = {0.f, 0.f, 0.f, 0.f};
    const int sb = t >> 4;             // 0..15 staging b
    const int sk = (t & 15) * 4;       // staging k (float4)

    for (int k0 = 0; k0 < UNITS; k0 += 64) {
        const float4 hv = *(const float4*)(hidden + (size_t)(bb + sb) * UNITS + k0 + sk);
        __syncthreads();
        *(float4*)&hT[sb * 68 + sk] = hv;
        __syncthreads();
        const float* wp = W2 + (size_t)k0 * UNITS + j;
#pragma unroll 4
        for (int k = 0; k < 64; ++k) {
            const float w = wp[(size_t)k * UNITS];
            acc[0] = fmaf(hT[(b0 + 0) * 68 + k], w, acc[0]);
            acc[1] = fmaf(hT[(b0 + 1) * 68 + k], w, acc[1]);
            acc[2] = fmaf(hT[(b0 + 2) * 68 + k], w, acc[2]);
            acc[3] = fmaf(hT[(b0 + 3) * 68 + k], w, acc[3]);
        }
    }
    const float bias = b1[j] + b2[j];
#pragma unroll
    for (int i = 0; i < 4; ++i)
        c[(size_t)(bb + b0 + i) * UNITS + j] = acc[i] + bias;
}

// ---------------- K2: score via bf16 MFMA (unchanged) -------------------------------
__global__ __launch_bounds__(256, 2) void k_score(const float* __restrict__ enc,
                                                  const float* __restrict__ W1,
                                                  const float* __restrict__ c,
                                                  const float* __restrict__ V,
                                                  float* __restrict__ score) {
    __shared__ unsigned short As[128 * 72];
    __shared__ unsigned short Bs[128 * 72];
    const int jt   = blockIdx.x;
    const int b    = blockIdx.y;
    const int tid  = threadIdx.x;
    const int lane = tid & 63;
    const int wid  = tid >> 6;
    const int wr   = wid & 1;
    const int wc   = wid >> 1;
    const int quad = lane >> 4;
    const int l16  = lane & 15;

    const float* encb = enc + (size_t)b * TLEN * UNITS;
    const float* w1b  = W1 + jt * 128;

    f32x4 acc[4][4];
#pragma unroll
    for (int i = 0; i < 4; ++i)
#pragma unroll
        for (int j = 0; j < 4; ++j)
            acc[i][j] = (f32x4){0.f, 0.f, 0.f, 0.f};

    const int ar = tid >> 4;
    const int ac = tid & 15;
    const int bp = tid >> 5;
    const int bj = tid & 31;

    for (int kc = 0; kc < UNITS; kc += 64) {
        float4 av[8];
#pragma unroll
        for (int rr = 0; rr < 8; ++rr)
            av[rr] = *(const float4*)(encb + (size_t)(ar + rr * 16) * UNITS + kc + ac * 4);
        float4 bv0[4], bv1[4];
#pragma unroll
        for (int kk = 0; kk < 4; ++kk) {
            const int k0 = 2 * (bp + 8 * kk);
            bv0[kk] = *(const float4*)(w1b + (size_t)(kc + k0) * UNITS + bj * 4);
            bv1[kk] = *(const float4*)(w1b + (size_t)(kc + k0 + 1) * UNITS + bj * 4);
        }
        __syncthreads();
#pragma unroll
        for (int rr = 0; rr < 8; ++rr) {
            ushort4 h;
            h.x = f2bf(av[rr].x); h.y = f2bf(av[rr].y);
            h.z = f2bf(av[rr].z); h.w = f2bf(av[rr].w);
            *(ushort4*)&As[(ar + rr * 16) * 72 + ac * 4] = h;
        }
#pragma unroll
        for (int kk = 0; kk < 4; ++kk) {
            const int k0 = 2 * (bp + 8 * kk);
            *(unsigned int*)&Bs[(bj * 4 + 0) * 72 + k0] = packbf(bv0[kk].x, bv1[kk].x);
            *(unsigned int*)&Bs[(bj * 4 + 1) * 72 + k0] = packbf(bv0[kk].y, bv1[kk].y);
            *(unsigned int*)&Bs[(bj * 4 + 2) * 72 + k0] = packbf(bv0[kk].z, bv1[kk].z);
            *(unsigned int*)&Bs[(bj * 4 + 3) * 72 + k0] = packbf(bv0[kk].w, bv1[kk].w);
        }
        __syncthreads();
#pragma unroll
        for (int kk = 0; kk < 2; ++kk) {
            const int kb = kk * 32 + quad * 8;
            short8 af[4], bfr[4];
#pragma unroll
            for (int mt = 0; mt < 4; ++mt)
                af[mt] = *(const short8*)&As[(wr * 64 + mt * 16 + l16) * 72 + kb];
#pragma unroll
            for (int nt = 0; nt < 4; ++nt)
                bfr[nt] = *(const short8*)&Bs[(wc * 64 + nt * 16 + l16) * 72 + kb];
#pragma unroll
            for (int mt = 0; mt < 4; ++mt)
#pragma unroll
                for (int nt = 0; nt < 4; ++nt)
                    acc[mt][nt] = __builtin_amdgcn_mfma_f32_16x16x32_bf16(
                        af[mt], bfr[nt], acc[mt][nt], 0, 0, 0);
        }
    }

    float cv[4], vv[4];
#pragma unroll
    for (int nt = 0; nt < 4; ++nt) {
        const int col = wc * 64 + nt * 16 + l16;
        cv[nt] = c[(size_t)b * UNITS + jt * 128 + col];
        vv[nt] = V[jt * 128 + col];
    }
    float rs[16];
#pragma unroll
    for (int mt = 0; mt < 4; ++mt)
#pragma unroll
        for (int reg = 0; reg < 4; ++reg) {
            float s = 0.f;
#pragma unroll
            for (int nt = 0; nt < 4; ++nt)
                s += tanhf(acc[mt][nt][reg] + cv[nt]) * vv[nt];
            rs[mt * 4 + reg] = s;
        }
#pragma unroll
    for (int off = 1; off < 16; off <<= 1)
#pragma unroll
        for (int i = 0; i < 16; ++i)
            rs[i] += __shfl_xor(rs[i], off);
    if (l16 == 0) {
#pragma unroll
        for (int mt = 0; mt < 4; ++mt)
#pragma unroll
            for (int reg = 0; reg < 4; ++reg)
                atomicAdd(&score[b * TLEN + wr * 64 + mt * 16 + quad * 4 + reg],
                          rs[mt * 4 + reg]);
    }
}

// ---------------- K3: softmax over t ------------------------------------------------
__global__ void k_softmax(const float* __restrict__ score, float* __restrict__ attw) {
    const int b = blockIdx.x;
    const int lane = threadIdx.x;
    float s0 = score[b * TLEN + lane];
    float s1 = score[b * TLEN + 64 + lane];
    float m = fmaxf(s0, s1);
#pragma unroll
    for (int off = 1; off < 64; off <<= 1) m = fmaxf(m, __shfl_xor(m, off));
    const float e0 = expf(s0 - m);
    const float e1 = expf(s1 - m);
    float s = e0 + e1;
#pragma unroll
    for (int off = 1; off < 64; off <<= 1) s += __shfl_xor(s, off);
    const float inv = 1.f / s;
    attw[b * TLEN + lane] = e0 * inv;
    attw[b * TLEN + 64 + lane] = e1 * inv;
}

// ---------------- K4: context -> gin[:, :1024] --------------------------------------
__global__ __launch_bounds__(256) void k_context(const float* __restrict__ enc,
                                                 const float* __restrict__ attw,
                                                 float* __restrict__ gin) {
    const int b = blockIdx.y;
    const int k = blockIdx.x * 256 + threadIdx.x;
    __shared__ float w[TLEN];
    if (threadIdx.x < TLEN) w[threadIdx.x] = attw[b * TLEN + threadIdx.x];
    __syncthreads();
    const float* e = enc + (size_t)b * TLEN * UNITS + k;
    float acc = 0.f;
#pragma unroll 8
    for (int t = 0; t < TLEN; ++t)
        acc = fmaf(w[t], e[(size_t)t * UNITS], acc);
    gin[(size_t)b * GIN_D + k] = acc;
}

// ---------------- K5: embedding gather -> gin[:, 1024:1280] -------------------------
__global__ void k_embed(const int* __restrict__ x, const float* __restrict__ emb,
                        float* __restrict__ gin) {
    const int b = blockIdx.x;
    const int e = threadIdx.x;
    const int row = x[b];
    gin[(size_t)b * GIN_D + UNITS + e] = emb[(size_t)row * EMBD + e];
}

// ---------------- K6: GRU fused (gates + finalize, no atomics) ----------------------
// block = 64 i-cols x 16 batches (4/thread), full K=1280. gin chunk in LDS.
// GRID MUST BE dim3(16,4): 16*64=1024 i-cols. (R4 bug: 32 x-blocks stomped state.)
__global__ __launch_bounds__(256) void k_gru(const float* __restrict__ gin,
                                             const float* __restrict__ gru_k,
                                             const float* __restrict__ gru_b,
                                             float* __restrict__ state,
                                             float* __restrict__ stateT) {
    __shared__ float gT[16 * 68];
    const int t    = threadIdx.x;
    const int lane = t & 63;
    const int wid  = t >> 6;
    const int i    = blockIdx.x * 64 + lane;
    const int bb   = blockIdx.y * 16;
    const int b0   = wid * 4;

    float az[4] = {0.f, 0.f, 0.f, 0.f};
    float ah[4] = {0.f, 0.f, 0.f, 0.f};
    const int sb = t >> 4;
    const int sk = (t & 15) * 4;

    for (int k0 = 0; k0 < GIN_D; k0 += 64) {
        const float4 gv = *(const float4*)(gin + (size_t)(bb + sb) * GIN_D + k0 + sk);
        __syncthreads();
        *(float4*)&gT[sb * 68 + sk] = gv;
        __syncthreads();
        const float* wz = gru_k + (size_t)k0 * 3072 + i;
        const float* wh = wz + 2048;
#pragma unroll 4
        for (int k = 0; k < 64; ++k) {
            const float z = wz[(size_t)k * 3072];
            const float h = wh[(size_t)k * 3072];
            const float g0 = gT[(b0 + 0) * 68 + k];
            const float g1 = gT[(b0 + 1) * 68 + k];
            const float g2 = gT[(b0 + 2) * 68 + k];
            const float g3 = gT[(b0 + 3) * 68 + k];
            az[0] = fmaf(g0, z, az[0]); ah[0] = fmaf(g0, h, ah[0]);
            az[1] = fmaf(g1, z, az[1]); ah[1] = fmaf(g1, h, ah[1]);
            az[2] = fmaf(g2, z, az[2]); ah[2] = fmaf(g2, h, ah[2]);
            az[3] = fmaf(g3, z, az[3]); ah[3] = fmaf(g3, h, ah[3]);
        }
    }
    const float bz = gru_b[i];
    const float bh = gru_b[2048 + i];
#pragma unroll
    for (int ii = 0; ii < 4; ++ii) {
        const float z  = 1.f / (1.f + expf(-(az[ii] + bz)));
        const float hh = tanhf(ah[ii] + bh);
        const float st = (1.f - z) * hh;
        const int b = bb + b0 + ii;
        state[(size_t)b * UNITS + i] = st;
        stateT[(size_t)i * BATCH + b] = st;
    }
}

// ---------------- K7: logits = state@fc_W + fc_b (fp32, LDS state, no atomics) ------
// block = 256 cols (64/wave) x 16 batches (all 16/thread), full K=1024.
__global__ __launch_bounds__(256) void k_fc(const float* __restrict__ stateT,
                                            const float* __restrict__ fc_W,
                                            const float* __restrict__ fc_b,
                                            float* __restrict__ logits) {
    __shared__ float sT[64 * 16];      // [k][b] chunk — linear copy of stateT slice
    const int t    = threadIdx.x;
    const int lane = t & 63;
    const int wid  = t >> 6;
    const int col  = blockIdx.x * 256 + wid * 64 + lane;
    const int bb   = blockIdx.y * 16;

    float acc[16];
#pragma unroll
    for (int i = 0; i < 16; ++i) acc[i] = 0.f;

    const int sk = t >> 2;             // staging: k row 0..63
    const int sbb = (t & 3) * 4;       // staging: b quad

    for (int k0 = 0; k0 < UNITS; k0 += 64) {
        const float4 sv = *(const float4*)(stateT + (size_t)(k0 + sk) * BATCH + bb + sbb);
        __syncthreads();
        *(float4*)&sT[sk * 16 + sbb] = sv;
        __syncthreads();
        const float* wp = fc_W + (size_t)k0 * VOCAB + col;
#pragma unroll 4
        for (int k = 0; k < 64; ++k) {
            const float w = wp[(size_t)k * VOCAB];
            const float4 s0 = *(const float4*)&sT[k * 16 + 0];
            const float4 s1 = *(const float4*)&sT[k * 16 + 4];
            const float4 s2 = *(const float4*)&sT[k * 16 + 8];
            const float4 s3 = *(const float4*)&sT[k * 16 + 12];
            acc[0]  = fmaf(s0.x, w, acc[0]);  acc[1]  = fmaf(s0.y, w, acc[1]);
            acc[2]  = fmaf(s0.z, w, acc[2]);  acc[3]  = fmaf(s0.w, w, acc[3]);
            acc[4]  = fmaf(s1.x, w, acc[4]);  acc[5]  = fmaf(s1.y, w, acc[5]);
            acc[6]  = fmaf(s1.z, w, acc[6]);  acc[7]  = fmaf(s1.w, w, acc[7]);
            acc[8]  = fmaf(s2.x, w, acc[8]);  acc[9]  = fmaf(s2.y, w, acc[9]);
            acc[10] = fmaf(s2.z, w, acc[10]); acc[11] = fmaf(s2.w, w, acc[11]);
            acc[12] = fmaf(s3.x, w, acc[12]); acc[13] = fmaf(s3.y, w, acc[13]);
            acc[14] = fmaf(s3.z, w, acc[14]); acc[15] = fmaf(s3.w, w, acc[15]);
        }
    }
    const float fb = fc_b[col];
#pragma unroll
    for (int i = 0; i < 16; ++i)
        logits[(size_t)(bb + i) * VOCAB + col] = acc[i] + fb;
}

extern "C" void kernel_launch(void* const* d_in, const int* in_sizes, int n_in,
                              void* d_out, int out_size, void* d_ws, size_t ws_size,
                              hipStream_t stream) {
    const int*   x      = (const int*)  d_in[0];
    const float* hidden = (const float*)d_in[1];
    const float* enc    = (const float*)d_in[2];
    const float* emb    = (const float*)d_in[3];
    const float* W1     = (const float*)d_in[4];
    const float* b1     = (const float*)d_in[5];
    const float* W2     = (const float*)d_in[6];
    const float* b2     = (const float*)d_in[7];
    const float* V      = (const float*)d_in[8];
    // d_in[9] = bV: softmax-invariant. d_in[11] = gru_rk: multiplies h0==0. Both unused.
    const float* gru_k  = (const float*)d_in[10];
    const float* gru_b  = (const float*)d_in[12];
    const float* fc_W   = (const float*)d_in[13];
    const float* fc_b   = (const float*)d_in[14];

    float* out       = (float*)d_out;
    float* logits    = out;                          // 64*32000
    float* state_out = out + (size_t)BATCH * VOCAB;  // 64*1024
    float* attw      = state_out + (size_t)BATCH * UNITS;  // 64*128

    float* c      = (float*)d_ws;        // 65536 f
    float* score  = c + 65536;           // 8192 f
    float* gin    = score + 8192;        // 81920 f
    float* stateT = gin + 81920;         // 65536 f

    hipMemsetAsync(score, 0, (size_t)BATCH * TLEN * sizeof(float), stream);

    k_c      <<<dim3(16, 4),  256, 0, stream>>>(hidden, W2, b1, b2, c);
    k_score  <<<dim3(8, 64),  256, 0, stream>>>(enc, W1, c, V, score);
    k_softmax<<<64, 64, 0, stream>>>(score, attw);
    k_context<<<dim3(4, 64),  256, 0, stream>>>(enc, attw, gin);
    k_embed  <<<64, 256, 0, stream>>>(x, emb, gin);
    k_gru    <<<dim3(16, 4),  256, 0, stream>>>(gin, gru_k, gru_b, state_out, stateT);
    k_fc     <<<dim3(125, 4), 256, 0, stream>>>(stateT, fc_W, fc_b, logits);
}